// Round 1
// 1118.399 us; speedup vs baseline: 1.0135x; 1.0135x over previous
//
#include <hip/hip_runtime.h>
#include <hip/hip_bf16.h>

// KarrasOptimalDenoiser: B=64, D=3072, N=50000.
// out[b] = softmax_n(-0.5*||x_b - Y_n||^2 / sigma_b^2) @ Y
// Round 2 changes vs round 1:
//   - score: 2-wave (128-thr) blocks, grid 1563 -> ~6.1 blocks/CU (was 782@4-wave
//     = 3.05/CU with +30% tail round); per-block online-softmax partials fused in
//     (softstat1 kernel deleted, saves a full sT re-read pass).
//   - softstat2: 1024 threads, 16-way ILP on the online-combine chain.
//   - f2bf via __float2bfloat16 (compiler can emit v_cvt_pk_bf16_f32 pairs).
//   - wsum/wprep/xpose structurally unchanged (isolate variables).

#define BB 64
#define DD 3072
#define NN 50000
#define NSPAD 50176    // 56*896, multiple of 64; rows >= NN zero-weighted
#define NGRP 384       // DD/8
#define SGRP 6272      // NSPAD/8
#define NCHK 896       // n per wsum chunk (28 k-steps)
#define SBLK 1563      // score blocks: ceil(50000/32)

typedef __attribute__((ext_vector_type(8))) short bf16x8;   // 8 bf16 = 4 VGPR
typedef __attribute__((ext_vector_type(4))) float f32x4;    // C/D frag

__device__ __forceinline__ unsigned short f2bf(float f) {   // fp32 -> bf16 RNE
  __hip_bfloat16 h = __float2bfloat16(f);
  return __builtin_bit_cast(unsigned short, h);
}
__device__ __forceinline__ float bf2f(unsigned short h) {
  return __uint_as_float(((unsigned)h) << 16);
}

// ---------------- xpose: pack X into A-frag layout [k/8][64b][8] ----------------
__global__ __launch_bounds__(256) void xpose_kernel(const float* __restrict__ x,
                                                    const float* __restrict__ sigma,
                                                    unsigned short* __restrict__ XhiP,
                                                    unsigned short* __restrict__ XloP,
                                                    float* __restrict__ x2g,
                                                    float* __restrict__ ivg) {
  const int b = blockIdx.x;
  const int t = threadIdx.x;
  const float4* xr = (const float4*)(x + (long)b * DD);
  float ss = 0.f;
#pragma unroll
  for (int i = 0; i < 3; ++i) {
    int idx = t + i * 256;        // 768 float4 per row
    float4 v = xr[idx];
    int grp = idx >> 1;
    int off = (idx & 1) * 4;      // k%8 in {0,4}
    ushort4 hh, ll;
    hh.x = f2bf(v.x); ll.x = f2bf(v.x - bf2f(hh.x));
    hh.y = f2bf(v.y); ll.y = f2bf(v.y - bf2f(hh.y));
    hh.z = f2bf(v.z); ll.z = f2bf(v.z - bf2f(hh.z));
    hh.w = f2bf(v.w); ll.w = f2bf(v.w - bf2f(hh.w));
    long o = ((long)grp * 64 + b) * 8 + off;
    *(ushort4*)(XhiP + o) = hh;
    *(ushort4*)(XloP + o) = ll;
    ss = fmaf(v.x, v.x, ss); ss = fmaf(v.y, v.y, ss);
    ss = fmaf(v.z, v.z, ss); ss = fmaf(v.w, v.w, ss);
  }
#pragma unroll
  for (int off = 32; off > 0; off >>= 1) ss += __shfl_down(ss, off, 64);
  __shared__ float red[4];
  if ((t & 63) == 0) red[t >> 6] = ss;
  __syncthreads();
  if (t == 0) {
    x2g[b] = red[0] + red[1] + red[2] + red[3];
    float sg = sigma[b];
    ivg[b] = 1.f / (sg * sg);
  }
}

// ---------------- score: sT[n][b] via MFMA + fused per-block softmax partials ----
// block = 2 waves (128 thr), wave w covers n in [blk*32 + w*16, +16), all 64 b
__global__ __launch_bounds__(128) void score_kernel(const float* __restrict__ Y,
                                                    const unsigned short* __restrict__ XhiP,
                                                    const unsigned short* __restrict__ XloP,
                                                    const float* __restrict__ x2g,
                                                    const float* __restrict__ ivg,
                                                    float* __restrict__ sT,
                                                    float* __restrict__ pM,
                                                    float* __restrict__ pL) {
  const int t = threadIdx.x;
  const int w = t >> 6;
  const int l = t & 63;
  const int l15 = l & 15, q = l >> 4;
  const int n = blockIdx.x * 32 + w * 16 + l15;
  const long nc = (n < NN) ? n : (NN - 1);          // clamp: junk rows zero-weighted later
  const float* yrow = Y + nc * (long)DD + q * 8;

  __shared__ float x2s[64], ivs[64];
  __shared__ float tr[2][16][68];                    // per-wave transpose buffer
  __shared__ float swm[2][64], swl[2][64];           // per-wave softmax partials
  if (t < 64) { x2s[t] = x2g[t]; ivs[t] = ivg[t]; }
  __syncthreads();

  f32x4 acc[4] = {};
  float y2 = 0.f;

  for (int kt = 0; kt < DD; kt += 32) {
    float4 b0 = *(const float4*)(yrow + kt);
    float4 b1 = *(const float4*)(yrow + kt + 4);
    const int grp = (kt >> 3) + q;
    const bf16x8* Ah = (const bf16x8*)XhiP + (long)grp * 64 + l15;
    const bf16x8* Al = (const bf16x8*)XloP + (long)grp * 64 + l15;
    bf16x8 a_h[4], a_l[4];
#pragma unroll
    for (int mt = 0; mt < 4; ++mt) { a_h[mt] = Ah[mt * 16]; a_l[mt] = Al[mt * 16]; }

    y2 = fmaf(b0.x, b0.x, y2); y2 = fmaf(b0.y, b0.y, y2);
    y2 = fmaf(b0.z, b0.z, y2); y2 = fmaf(b0.w, b0.w, y2);
    y2 = fmaf(b1.x, b1.x, y2); y2 = fmaf(b1.y, b1.y, y2);
    y2 = fmaf(b1.z, b1.z, y2); y2 = fmaf(b1.w, b1.w, y2);

    float fv[8] = {b0.x, b0.y, b0.z, b0.w, b1.x, b1.y, b1.z, b1.w};
    bf16x8 bh, bl;
#pragma unroll
    for (int j = 0; j < 8; ++j) {
      unsigned short h = f2bf(fv[j]);
      bh[j] = (short)h;
      bl[j] = (short)f2bf(fv[j] - bf2f(h));
    }
#pragma unroll
    for (int mt = 0; mt < 4; ++mt) {
      acc[mt] = __builtin_amdgcn_mfma_f32_16x16x32_bf16(a_h[mt], bh, acc[mt], 0, 0, 0);
      acc[mt] = __builtin_amdgcn_mfma_f32_16x16x32_bf16(a_h[mt], bl, acc[mt], 0, 0, 0);
      acc[mt] = __builtin_amdgcn_mfma_f32_16x16x32_bf16(a_l[mt], bh, acc[mt], 0, 0, 0);
    }
  }

  // y2 partials live per (row=l15, k-quarter=q): reduce over q
  y2 += __shfl_xor(y2, 16, 64);
  y2 += __shfl_xor(y2, 32, 64);

  // transform, stage to LDS, keep register copy for the fused softmax partials
  float sv[4][4];
#pragma unroll
  for (int mt = 0; mt < 4; ++mt) {
#pragma unroll
    for (int r = 0; r < 4; ++r) {
      int b = mt * 16 + q * 4 + r;                   // C/D: row=q*4+r, col=l15
      float s = fminf(-0.5f * ivs[b] * (x2s[b] + y2 - 2.f * acc[mt][r]), 0.f);
      sv[mt][r] = s;
      tr[w][l15][b] = s;
    }
  }

  // fused per-block online-softmax partial (over this block's 16 n per wave).
  // Each (mt,r) is one b; its 16 n-values live across the 16 lanes of this q-group.
  const bool valid = (n < NN);
  const float NEG = -3.402823466e38f;
#pragma unroll
  for (int mt = 0; mt < 4; ++mt) {
#pragma unroll
    for (int r = 0; r < 4; ++r) {
      float s = valid ? sv[mt][r] : NEG;
      float sm = s;
      sm = fmaxf(sm, __shfl_xor(sm, 1, 64));
      sm = fmaxf(sm, __shfl_xor(sm, 2, 64));
      sm = fmaxf(sm, __shfl_xor(sm, 4, 64));
      sm = fmaxf(sm, __shfl_xor(sm, 8, 64));
      float e = valid ? __expf(sv[mt][r] - sm) : 0.f;
      e += __shfl_xor(e, 1, 64);
      e += __shfl_xor(e, 2, 64);
      e += __shfl_xor(e, 4, 64);
      e += __shfl_xor(e, 8, 64);
      if (l15 == 0) {
        int b = mt * 16 + q * 4 + r;
        swm[w][b] = sm;
        swl[w][b] = e;
      }
    }
  }
  __syncthreads();

  // coalesced sT write: lane l writes 64B of row (blk*32 + w*16 + l15)
  const long nrow = (long)blockIdx.x * 32 + w * 16 + l15;
  float* dst = sT + nrow * 64 + q * 16;
  const float* src = &tr[w][l15][q * 16];
  *(float4*)(dst + 0)  = *(const float4*)(src + 0);
  *(float4*)(dst + 4)  = *(const float4*)(src + 4);
  *(float4*)(dst + 8)  = *(const float4*)(src + 8);
  *(float4*)(dst + 12) = *(const float4*)(src + 12);

  // combine the 2 wave-partials -> block partial
  if (t < 64) {
    float m0 = swm[0][t], l0 = swl[0][t];
    float m1 = swm[1][t], l1 = swl[1][t];
    float nm = fmaxf(m0, m1);
    float ll = l0 * __expf(m0 - nm) + l1 * __expf(m1 - nm);
    pM[(long)blockIdx.x * 64 + t] = nm;
    pL[(long)blockIdx.x * 64 + t] = ll;
  }
}

// ---------------- softstat2: combine SBLK partials, 16-way ILP ----------------
__global__ __launch_bounds__(1024) void softstat2_kernel(const float* __restrict__ pM,
                                                         const float* __restrict__ pL,
                                                         float* __restrict__ mg,
                                                         float* __restrict__ rlg) {
  const int t = threadIdx.x;
  const int b = t & 63;
  const int g = t >> 6;            // 0..15
  float m = -3.402823466e38f, l = 0.f;
  for (int i = g; i < SBLK; i += 16) {
    float m2 = pM[(long)i * 64 + b], l2 = pL[(long)i * 64 + b];
    float nm = fmaxf(m, m2);
    l = fmaf(l, __expf(m - nm), l2 * __expf(m2 - nm));
    m = nm;
  }
  __shared__ float sm[1024], sl[1024];
  sm[t] = m; sl[t] = l;
  __syncthreads();
  if (g == 0) {
#pragma unroll
    for (int j = 1; j < 16; ++j) {
      float m2 = sm[j * 64 + b], l2 = sl[j * 64 + b];
      float nm = fmaxf(m, m2);
      l = fmaf(l, __expf(m - nm), l2 * __expf(m2 - nm));
      m = nm;
    }
    mg[b] = m;
    rlg[b] = 1.f / l;
  }
}

// ---------------- wprep: w -> A-frag bf16 hi/lo [n/8][64b][8] ----------------
__global__ __launch_bounds__(256) void wprep_kernel(const float* __restrict__ sT,
                                                    const float* __restrict__ mg,
                                                    const float* __restrict__ rlg,
                                                    unsigned short* __restrict__ WH,
                                                    unsigned short* __restrict__ WL) {
  const int t = threadIdx.x;
  const int b = t & 63;
  const int grp = blockIdx.x * 4 + (t >> 6);     // grid 1568 -> grp < 6272
  const float mb = mg[b], rb = rlg[b];
  bf16x8 H, L;
#pragma unroll
  for (int j = 0; j < 8; ++j) {
    int n = grp * 8 + j;
    float s = sT[(long)n * 64 + b];
    float wv = (n < NN) ? __expf(s - mb) * rb : 0.f;   // zero out pad rows (incl. NaN poison)
    unsigned short h = f2bf(wv);
    H[j] = (short)h;
    L[j] = (short)f2bf(wv - bf2f(h));
  }
  *((bf16x8*)WH + (long)grp * 64 + b) = H;
  *((bf16x8*)WL + (long)grp * 64 + b) = L;
}

// ---------------- wsum: out[b][d] += w @ Y via MFMA ----------------
// block = 4 waves; wave w covers d in [dblk*128 + w*32, +32) (2 d-tiles), all 64 b
__global__ __launch_bounds__(256) void wsum_kernel(const float* __restrict__ Y,
                                                   const unsigned short* __restrict__ WH,
                                                   const unsigned short* __restrict__ WL,
                                                   float* __restrict__ out) {
  const int t = threadIdx.x;
  const int w = t >> 6;
  const int l = t & 63;
  const int l15 = l & 15, q = l >> 4;
  const int dblk = blockIdx.x % 24;
  const int c = blockIdx.x / 24;                  // 56 n-chunks
  const int d0 = dblk * 128 + w * 32 + l15;
  const int nstart = c * NCHK;

  f32x4 acc[4][2] = {};

  for (int k0 = nstart; k0 < nstart + NCHK; k0 += 32) {
    const int grp = (k0 >> 3) + q;
    const bf16x8* Ah = (const bf16x8*)WH + (long)grp * 64 + l15;
    const bf16x8* Al = (const bf16x8*)WL + (long)grp * 64 + l15;
    bf16x8 wh[4], wl[4];
#pragma unroll
    for (int mt = 0; mt < 4; ++mt) { wh[mt] = Ah[mt * 16]; wl[mt] = Al[mt * 16]; }

    const int rbase = k0 + q * 8;
    float f0[8], f1[8];
#pragma unroll
    for (int j = 0; j < 8; ++j) {
      long r = rbase + j;
      r = (r < NN) ? r : (NN - 1);                // clamped; weight is 0 there
      const float* yp = Y + r * (long)DD + d0;
      f0[j] = yp[0];
      f1[j] = yp[16];
    }
    bf16x8 yh0, yl0, yh1, yl1;
#pragma unroll
    for (int j = 0; j < 8; ++j) {
      unsigned short h0 = f2bf(f0[j]);
      yh0[j] = (short)h0; yl0[j] = (short)f2bf(f0[j] - bf2f(h0));
      unsigned short h1 = f2bf(f1[j]);
      yh1[j] = (short)h1; yl1[j] = (short)f2bf(f1[j] - bf2f(h1));
    }
#pragma unroll
    for (int mt = 0; mt < 4; ++mt) {
      acc[mt][0] = __builtin_amdgcn_mfma_f32_16x16x32_bf16(wh[mt], yh0, acc[mt][0], 0, 0, 0);
      acc[mt][0] = __builtin_amdgcn_mfma_f32_16x16x32_bf16(wh[mt], yl0, acc[mt][0], 0, 0, 0);
      acc[mt][0] = __builtin_amdgcn_mfma_f32_16x16x32_bf16(wl[mt], yh0, acc[mt][0], 0, 0, 0);
      acc[mt][1] = __builtin_amdgcn_mfma_f32_16x16x32_bf16(wh[mt], yh1, acc[mt][1], 0, 0, 0);
      acc[mt][1] = __builtin_amdgcn_mfma_f32_16x16x32_bf16(wh[mt], yl1, acc[mt][1], 0, 0, 0);
      acc[mt][1] = __builtin_amdgcn_mfma_f32_16x16x32_bf16(wl[mt], yh1, acc[mt][1], 0, 0, 0);
    }
  }

#pragma unroll
  for (int mt = 0; mt < 4; ++mt)
#pragma unroll
    for (int dt = 0; dt < 2; ++dt)
#pragma unroll
      for (int r = 0; r < 4; ++r) {
        int b = mt * 16 + q * 4 + r;
        unsafeAtomicAdd(&out[(long)b * DD + d0 + dt * 16], acc[mt][dt][r]);
      }
}

extern "C" void kernel_launch(void* const* d_in, const int* in_sizes, int n_in,
                              void* d_out, int out_size, void* d_ws, size_t ws_size,
                              hipStream_t stream) {
  const float* x = (const float*)d_in[0];      // [64,3,32,32]
  const float* sigma = (const float*)d_in[1];  // [64]
  const float* Y = (const float*)d_in[2];      // [50000,3,32,32]
  float* out = (float*)d_out;

  char* p = (char*)d_ws;
  float* sT = (float*)p;            p += (long)NSPAD * 64 * 4;   // 12.85 MB
  unsigned short* WH = (unsigned short*)p; p += (long)NSPAD * 64 * 2;  // 6.4 MB
  unsigned short* WL = (unsigned short*)p; p += (long)NSPAD * 64 * 2;  // 6.4 MB
  unsigned short* XhiP = (unsigned short*)p; p += (long)NGRP * 64 * 8 * 2;  // 384 KB
  unsigned short* XloP = (unsigned short*)p; p += (long)NGRP * 64 * 8 * 2;  // 384 KB
  float* x2g = (float*)p; p += 64 * 4;
  float* ivg = (float*)p; p += 64 * 4;
  float* mg  = (float*)p; p += 64 * 4;
  float* rlg = (float*)p; p += 64 * 4;
  float* pM  = (float*)p; p += (long)SBLK * 64 * 4;   // 400 KB
  float* pL  = (float*)p; p += (long)SBLK * 64 * 4;   // 400 KB
  // total ws use ~27.3 MB

  hipMemsetAsync(d_out, 0, (size_t)out_size * sizeof(float), stream);
  hipLaunchKernelGGL(xpose_kernel, dim3(BB), dim3(256), 0, stream,
                     x, sigma, XhiP, XloP, x2g, ivg);
  hipLaunchKernelGGL(score_kernel, dim3(SBLK), dim3(128), 0, stream,
                     Y, XhiP, XloP, x2g, ivg, sT, pM, pL);
  hipLaunchKernelGGL(softstat2_kernel, dim3(1), dim3(1024), 0, stream, pM, pL, mg, rlg);
  hipLaunchKernelGGL(wprep_kernel, dim3(SGRP / 4), dim3(256), 0, stream,
                     sT, mg, rlg, WH, WL);
  hipLaunchKernelGGL(wsum_kernel, dim3(24 * 56), dim3(256), 0, stream,
                     Y, WH, WL, out);
}